// Round 1
// baseline (883.019 us; speedup 1.0000x reference)
//
#include <hip/hip_runtime.h>
#include <hip/hip_bf16.h>
#include <math.h>

typedef __bf16 bf16_t;
typedef __attribute__((ext_vector_type(8))) __bf16 bf16x8;
typedef __attribute__((ext_vector_type(4))) __bf16 bf16x4;
typedef __attribute__((ext_vector_type(4))) float f32x4;

#define NTOK 8192   // B*T
#define HDIM 1024
#define DFF  4096
#define RHID 512

__device__ __forceinline__ float gelu_exact(float v) {
  return 0.5f * v * (1.0f + erff(v * 0.70710678118654752f));
}

// tanh-form gelu via sigmoid; max abs err ~3e-4 (noise vs bf16 quantization).
__device__ __forceinline__ float gelu_fast(float v) {
  const float g = 1.5957691216057308f * (v + 0.044715f * v * v * v);
  return v / (1.0f + __expf(-g));
}

__device__ __forceinline__ void async_cp16(void* lds, const void* g) {
  __builtin_amdgcn_global_load_lds(
      (__attribute__((address_space(1))) void*)g,
      (__attribute__((address_space(3))) void*)lds, 16, 0, 0);
}

// XCD-aware remap for 128x128 tile grids (router + k_gemm).
__device__ __forceinline__ void remap_tile(int g, int& mt, int& nt) {
  mt = ((g & 7) << 3) | ((g >> 3) & 7);
  nt = g >> 6;
}

// ---------------------------------------------------------------------------
// GEMM1 256x256 tile, BK=64, 8 waves (2x4), double-buffered 128 KiB LDS,
// 4-phase counted-vmcnt pipeline (T2+T3+T4+T5 per the technique catalog).
// LDS per buffer: A = [mh(2)][128 rows][8 slots*16B] (32 KiB), B likewise for
// columns; LDS row r, slot s holds global k-slot (s ^ (r&7)) — swizzle applied
// on the GLOBAL source so global_load_lds writes linearly (m173 pattern).
// A LDS row rl = mh*128 + q maps to global row q<64 ? mh*64+q : 128+mh*64+q-64.
// B LDS row rl = nh*128 + q maps to global col (q>>5)*64 + nh*32 + (q&31).
// Phase p computes one C-quadrant (mh,nh); stages one half-group of tile t+1.
// vmcnt schedule per tile: issue A0,B0,A1,B1 (2 loads each);
//   end-P1 vmcnt(2) (A1,B1 of tile t landed), end-P4 vmcnt(4) (A0,B0 of t+1).
// ---------------------------------------------------------------------------
__device__ __forceinline__ void body_tile256(
    int mt, int nt,
    const bf16_t* __restrict__ A, const bf16_t* __restrict__ Bt,
    const float* __restrict__ bias, bf16_t* __restrict__ Hout,
    int N, int K, char* sm)
{
  const int tid  = threadIdx.x;
  const int lane = tid & 63;
  const int wv   = tid >> 6;      // 0..7
  const int wm   = wv >> 2;       // 0..1
  const int wn   = wv & 3;        // 0..3
  const int lr   = lane & 15;
  const int quad = lane >> 4;
  const int m0 = mt * 256;
  const int n0 = nt * 256;

  char* const Ab0 = sm;
  char* const Bb0 = sm + 32768;
  char* const Ab1 = sm + 65536;
  char* const Bb1 = sm + 98304;

  // read-side swizzled slot offsets (rl&7 == lr&7 for all our frag rows)
  const int sw0 = ((quad ^ (lr & 7)) << 4);
  const int sw1 = (((quad + 4) ^ (lr & 7)) << 4);
  const int aRowB = (wm * 64 + lr) << 7;   // + mh*16384 + i*2048
  const int bRowB = (wn * 32 + lr) << 7;   // + nh*16384 + j*2048

  f32x4 acc[8][4];
#pragma unroll
  for (int i = 0; i < 8; ++i)
#pragma unroll
    for (int j = 0; j < 4; ++j)
      acc[i][j] = (f32x4){0.f, 0.f, 0.f, 0.f};

  // staging sources (pre-swizzled k-slot within each row)
  const int srow = tid >> 3;                          // 0..63
  const int seo  = (((tid & 7) ^ (srow & 7)) << 3);   // elems
  const bf16_t* const aS00 = A + (size_t)(m0 +       srow) * K + seo;
  const bf16_t* const aS01 = A + (size_t)(m0 + 128 + srow) * K + seo;
  const bf16_t* const aS10 = A + (size_t)(m0 +  64 + srow) * K + seo;
  const bf16_t* const aS11 = A + (size_t)(m0 + 192 + srow) * K + seo;
  const int bc0 = ((srow >> 5) << 6) + (srow & 31);   // {0..31, 64..95}
  const bf16_t* const bS00 = Bt + (size_t)(n0 +       bc0) * K + seo;
  const bf16_t* const bS01 = Bt + (size_t)(n0 + 128 + bc0) * K + seo;
  const bf16_t* const bS10 = Bt + (size_t)(n0 +  32 + bc0) * K + seo;
  const bf16_t* const bS11 = Bt + (size_t)(n0 + 160 + bc0) * K + seo;
  const int dst = tid << 4;

  // prologue: K-tile 0 into buf0, issue order A0,B0,A1,B1 (matches loop)
  async_cp16(Ab0 + dst,                aS00);
  async_cp16(Ab0 + dst + 8192,         aS01);
  async_cp16(Bb0 + dst,                bS00);
  async_cp16(Bb0 + dst + 8192,         bS01);
  async_cp16(Ab0 + 16384 + dst,        aS10);
  async_cp16(Ab0 + 16384 + dst + 8192, aS11);
  async_cp16(Bb0 + 16384 + dst,        bS10);
  async_cp16(Bb0 + 16384 + dst + 8192, bS11);
  asm volatile("s_waitcnt vmcnt(4)" ::: "memory");
  __builtin_amdgcn_s_barrier();

  bf16x8 a0[4], a1[4], b00[2], b01[2], b10[2], b11[2];

  const int NT = K >> 6;
  for (int t = 0; t < NT; ++t) {
    char* const Ac = (t & 1) ? Ab1 : Ab0;
    char* const Bc = (t & 1) ? Bb1 : Bb0;
    char* const An = (t & 1) ? Ab0 : Ab1;
    char* const Bn = (t & 1) ? Bb0 : Bb1;
    // last tile: re-stage current addresses (valid, never read) to keep counts
    const size_t kbn = (size_t)((t + 1 < NT) ? t + 1 : t) << 6;

    // ---- P1: quadrant (mh0, nh0); reads A-half0 + B-half0; stage A0(t+1) ----
#pragma unroll
    for (int i = 0; i < 4; ++i) {
      const char* p = Ac + aRowB + i * 2048;
      a0[i] = *(const bf16x8*)(p + sw0);
      a1[i] = *(const bf16x8*)(p + sw1);
    }
#pragma unroll
    for (int j = 0; j < 2; ++j) {
      const char* p = Bc + bRowB + j * 2048;
      b00[j] = *(const bf16x8*)(p + sw0);
      b01[j] = *(const bf16x8*)(p + sw1);
    }
    async_cp16(An + dst,        aS00 + kbn);
    async_cp16(An + dst + 8192, aS01 + kbn);
    __builtin_amdgcn_s_barrier();
    asm volatile("s_waitcnt lgkmcnt(0)" ::: "memory");
    __builtin_amdgcn_sched_barrier(0);
    __builtin_amdgcn_s_setprio(1);
#pragma unroll
    for (int i = 0; i < 4; ++i)
#pragma unroll
      for (int j = 0; j < 2; ++j) {
        acc[i][j] = __builtin_amdgcn_mfma_f32_16x16x32_bf16(a0[i], b00[j], acc[i][j], 0, 0, 0);
        acc[i][j] = __builtin_amdgcn_mfma_f32_16x16x32_bf16(a1[i], b01[j], acc[i][j], 0, 0, 0);
      }
    __builtin_amdgcn_s_setprio(0);
    asm volatile("s_waitcnt vmcnt(2)" ::: "memory");
    __builtin_amdgcn_s_barrier();

    // ---- P2: quadrant (mh0, nh1); reads B-half1; stage B0(t+1) ----
#pragma unroll
    for (int j = 0; j < 2; ++j) {
      const char* p = Bc + 16384 + bRowB + j * 2048;
      b10[j] = *(const bf16x8*)(p + sw0);
      b11[j] = *(const bf16x8*)(p + sw1);
    }
    async_cp16(Bn + dst,        bS00 + kbn);
    async_cp16(Bn + dst + 8192, bS01 + kbn);
    __builtin_amdgcn_s_barrier();
    asm volatile("s_waitcnt lgkmcnt(0)" ::: "memory");
    __builtin_amdgcn_sched_barrier(0);
    __builtin_amdgcn_s_setprio(1);
#pragma unroll
    for (int i = 0; i < 4; ++i)
#pragma unroll
      for (int j = 0; j < 2; ++j) {
        acc[i][2+j] = __builtin_amdgcn_mfma_f32_16x16x32_bf16(a0[i], b10[j], acc[i][2+j], 0, 0, 0);
        acc[i][2+j] = __builtin_amdgcn_mfma_f32_16x16x32_bf16(a1[i], b11[j], acc[i][2+j], 0, 0, 0);
      }
    __builtin_amdgcn_s_setprio(0);
    __builtin_amdgcn_s_barrier();

    // ---- P3: quadrant (mh1, nh1); reads A-half1; stage A1(t+1) ----
#pragma unroll
    for (int i = 0; i < 4; ++i) {
      const char* p = Ac + 16384 + aRowB + i * 2048;
      a0[i] = *(const bf16x8*)(p + sw0);
      a1[i] = *(const bf16x8*)(p + sw1);
    }
    async_cp16(An + 16384 + dst,        aS10 + kbn);
    async_cp16(An + 16384 + dst + 8192, aS11 + kbn);
    __builtin_amdgcn_s_barrier();
    asm volatile("s_waitcnt lgkmcnt(0)" ::: "memory");
    __builtin_amdgcn_sched_barrier(0);
    __builtin_amdgcn_s_setprio(1);
#pragma unroll
    for (int i = 0; i < 4; ++i)
#pragma unroll
      for (int j = 0; j < 2; ++j) {
        acc[4+i][2+j] = __builtin_amdgcn_mfma_f32_16x16x32_bf16(a0[i], b10[j], acc[4+i][2+j], 0, 0, 0);
        acc[4+i][2+j] = __builtin_amdgcn_mfma_f32_16x16x32_bf16(a1[i], b11[j], acc[4+i][2+j], 0, 0, 0);
      }
    __builtin_amdgcn_s_setprio(0);
    __builtin_amdgcn_s_barrier();

    // ---- P4: quadrant (mh1, nh0); no reads; stage B1(t+1) ----
    async_cp16(Bn + 16384 + dst,        bS10 + kbn);
    async_cp16(Bn + 16384 + dst + 8192, bS11 + kbn);
    __builtin_amdgcn_s_barrier();
    __builtin_amdgcn_s_setprio(1);
#pragma unroll
    for (int i = 0; i < 4; ++i)
#pragma unroll
      for (int j = 0; j < 2; ++j) {
        acc[4+i][j] = __builtin_amdgcn_mfma_f32_16x16x32_bf16(a0[i], b00[j], acc[4+i][j], 0, 0, 0);
        acc[4+i][j] = __builtin_amdgcn_mfma_f32_16x16x32_bf16(a1[i], b01[j], acc[4+i][j], 0, 0, 0);
      }
    __builtin_amdgcn_s_setprio(0);
    asm volatile("s_waitcnt vmcnt(4)" ::: "memory");
    __builtin_amdgcn_s_barrier();
  }
  // drain pending LDS DMA before wave exit (LDS may be reassigned)
  asm volatile("s_waitcnt vmcnt(0)" ::: "memory");

  // epilogue: gelu -> bf16 (MODE 0 semantics, numerics identical to old path)
#pragma unroll
  for (int mh = 0; mh < 2; ++mh)
#pragma unroll
    for (int i = 0; i < 4; ++i)
#pragma unroll
      for (int r = 0; r < 4; ++r) {
        const int gm = m0 + wm * 128 + mh * 64 + i * 16 + quad * 4 + r;
        bf16_t* const orow = Hout + (size_t)gm * N + n0 + wn * 64 + lr;
#pragma unroll
        for (int nh = 0; nh < 2; ++nh)
#pragma unroll
          for (int j = 0; j < 2; ++j) {
            const int cn = nh * 32 + j * 16;
            const float v = acc[mh * 4 + i][nh * 2 + j][r] + bias[n0 + wn * 64 + cn + lr];
            orow[cn] = (bf16_t)gelu_fast(v);
          }
      }
}

// ---------------------------------------------------------------------------
// GEMM tile for k_gemm (MODE 1/2), unchanged proven r4 structure.
// ---------------------------------------------------------------------------
template<int MODE, bool WRITE_OUT, int WM, int WN>
__device__ __forceinline__ void body_tile(
    int mt, int nt,
    const bf16_t* __restrict__ A, const bf16_t* __restrict__ Bt,
    const float* __restrict__ bias, int N, int K,
    bf16_t* __restrict__ Hout, float* __restrict__ Xout,
    bf16_t* __restrict__ Xb, bf16_t* __restrict__ Xlo,
    const float* __restrict__ Wmix,
    bf16_t* As, bf16_t* Bs)
{
  constexpr int BM  = WM * 32;
  constexpr int BN  = WN * 32;
  constexpr int ACH = BM / 32;
  constexpr int BCH = BN / 32;
  const int tid  = threadIdx.x;
  const int lane = tid & 63;
  const int wv   = tid >> 6;
  const int wm   = wv >> 1;
  const int wn   = wv & 1;
  const int lr   = lane & 15;
  const int quad = lane >> 4;
  const int m0 = mt * BM;
  const int n0 = nt * BN;

  f32x4 acc[WM][WN];
#pragma unroll
  for (int i = 0; i < WM; ++i)
#pragma unroll
    for (int j = 0; j < WN; ++j)
      acc[i][j] = (f32x4){0.f, 0.f, 0.f, 0.f};

  const int c   = tid;
  const int row = c >> 3;
  const int ks  = (((c & 7) - (row & 7)) & 7) * 8;
  const bf16_t* Agb = A  + (size_t)(m0 + row) * K + ks;
  const bf16_t* Bgb = Bt + (size_t)(n0 + row) * K + ks;
  char* lAb = (char*)As + c * 16;
  char* lBb = (char*)Bs + c * 16;

  for (int kb = 0; kb < K; kb += 64) {
    __syncthreads();
#pragma unroll
    for (int t = 0; t < ACH; ++t)
      async_cp16(lAb + 4096 * t, Agb + (size_t)32 * t * K + kb);
#pragma unroll
    for (int t = 0; t < BCH; ++t)
      async_cp16(lBb + 4096 * t, Bgb + (size_t)32 * t * K + kb);
    __syncthreads();
#pragma unroll
    for (int kk = 0; kk < 2; ++kk) {
      const int kg = kk * 4 + quad;
      bf16x8 af[WM], bfr[WN];
#pragma unroll
      for (int i = 0; i < WM; ++i) {
        const int ra = wm * (WM * 16) + i * 16 + lr;
        af[i] = *(const bf16x8*)&As[ra * 64 + ((kg + ra) & 7) * 8];
      }
#pragma unroll
      for (int j = 0; j < WN; ++j) {
        const int rb = wn * (WN * 16) + j * 16 + lr;
        bfr[j] = *(const bf16x8*)&Bs[rb * 64 + ((kg + rb) & 7) * 8];
      }
#pragma unroll
      for (int i = 0; i < WM; ++i)
#pragma unroll
        for (int j = 0; j < WN; ++j)
          acc[i][j] = __builtin_amdgcn_mfma_f32_16x16x32_bf16(af[i], bfr[j], acc[i][j], 0, 0, 0);
    }
  }

#pragma unroll
  for (int i = 0; i < WM; ++i) {
#pragma unroll
    for (int r = 0; r < 4; ++r) {
      const int gm = m0 + wm * (WM * 16) + i * 16 + quad * 4 + r;
      float wmix = 0.f, onemw = 0.f;
      if (MODE == 2) { wmix = Wmix[gm]; onemw = 1.f - wmix; }
#pragma unroll
      for (int j = 0; j < WN; ++j) {
        const int gn = n0 + wn * (WN * 16) + j * 16 + lr;
        float v = acc[i][j][r] + bias[gn];
        if (MODE == 0) {
          Hout[(size_t)gm * N + gn] = (bf16_t)gelu_fast(v);
        } else {
          const size_t idx = (size_t)gm * N + gn;
          if (MODE == 2) {
            const float xold = (float)Xb[idx] + (float)Xlo[idx];
            v = wmix * v + onemw * xold;
          }
          const bf16_t hi = (bf16_t)v;
          Xb[idx]  = hi;
          Xlo[idx] = (bf16_t)(v - (float)hi);
          if (WRITE_OUT) Xout[idx] = v;
        }
      }
    }
  }
}

// ---------------------------------------------------------------------------
// Router tile (hi/lo split ~fp32) for 512-thread blocks: 8 waves 2x4,
// BK=32 single-buffered, 32KB LDS. acc = Ah*Bh + Al*Bh + Ah*Bl.
// ---------------------------------------------------------------------------
__device__ __forceinline__ void router_tile512(
    int mt, int nt,
    const bf16_t* __restrict__ Ah, const bf16_t* __restrict__ Al,
    const bf16_t* __restrict__ Bh, const bf16_t* __restrict__ Bl,
    const float* __restrict__ bias, float* __restrict__ Hr,
    bf16_t* Ahs, bf16_t* Als, bf16_t* Bhs, bf16_t* Bls)
{
  const int K = HDIM, N = RHID;
  const int tid  = threadIdx.x;
  const int lane = tid & 63;
  const int wv   = tid >> 6;
  const int wm   = wv >> 2;   // 0..1
  const int wn   = wv & 3;    // 0..3
  const int lr   = lane & 15;
  const int quad = lane >> 4;
  const int m0 = mt * 128;
  const int n0 = nt * 128;

  f32x4 acc[4][2];
#pragma unroll
  for (int i = 0; i < 4; ++i)
#pragma unroll
    for (int j = 0; j < 2; ++j)
      acc[i][j] = (f32x4){0.f, 0.f, 0.f, 0.f};

  const int r   = tid >> 2;                 // 0..127
  const int ks  = ((tid ^ r) & 3) * 8;
  const size_t aoff = (size_t)(m0 + r) * K + ks;
  const size_t boff = (size_t)(n0 + r) * K + ks;
  const int dst = tid << 4;
  const int sw  = ((quad ^ lr) & 3) * 8;

  for (int k0 = 0; k0 < K; k0 += 32) {
    __syncthreads();
    async_cp16((char*)Ahs + dst, Ah + aoff + k0);
    async_cp16((char*)Als + dst, Al + aoff + k0);
    async_cp16((char*)Bhs + dst, Bh + boff + k0);
    async_cp16((char*)Bls + dst, Bl + boff + k0);
    __syncthreads();
    bf16x8 ah[4], al[4], bh[2], bl[2];
#pragma unroll
    for (int i = 0; i < 4; ++i) {
      const int ao = (wm * 64 + i * 16 + lr) * 32 + sw;
      ah[i] = *(const bf16x8*)&Ahs[ao];
      al[i] = *(const bf16x8*)&Als[ao];
    }
#pragma unroll
    for (int j = 0; j < 2; ++j) {
      const int bo = (wn * 32 + j * 16 + lr) * 32 + sw;
      bh[j] = *(const bf16x8*)&Bhs[bo];
      bl[j] = *(const bf16x8*)&Bls[bo];
    }
#pragma unroll
    for (int i = 0; i < 4; ++i)
#pragma unroll
      for (int j = 0; j < 2; ++j) {
        acc[i][j] = __builtin_amdgcn_mfma_f32_16x16x32_bf16(ah[i], bh[j], acc[i][j], 0, 0, 0);
        acc[i][j] = __builtin_amdgcn_mfma_f32_16x16x32_bf16(al[i], bh[j], acc[i][j], 0, 0, 0);
        acc[i][j] = __builtin_amdgcn_mfma_f32_16x16x32_bf16(ah[i], bl[j], acc[i][j], 0, 0, 0);
      }
  }

#pragma unroll
  for (int i = 0; i < 4; ++i)
#pragma unroll
    for (int rr = 0; rr < 4; ++rr) {
      const int gm = m0 + wm * 64 + i * 16 + quad * 4 + rr;
#pragma unroll
      for (int j = 0; j < 2; ++j) {
        const int gn = n0 + wn * 32 + j * 16 + lr;
        Hr[(size_t)gm * N + gn] = gelu_exact(acc[i][j][rr] + bias[gn]);
      }
    }
}

// MODE1/MODE2 standalone GEMM, 128x128 tiles (512 blocks), 32KB LDS
template<int MODE, bool WRITE_OUT>
__global__ __launch_bounds__(256, 4)
void k_gemm(const bf16_t* __restrict__ A, const bf16_t* __restrict__ Bt,
            const float* __restrict__ bias, int N, int K,
            float* __restrict__ Xout, bf16_t* __restrict__ Xb,
            bf16_t* __restrict__ Xlo, const float* __restrict__ Wmix)
{
  __shared__ __align__(16) bf16_t sm[16384];
  int mt, nt;
  remap_tile(blockIdx.x, mt, nt);
  body_tile<MODE, WRITE_OUT, 4, 4>(mt, nt, A, Bt, bias, N, K,
                                   nullptr, Xout, Xb, Xlo, Wmix, sm, sm + 8192);
}

// GEMM1 (256^2 8-phase) + fused router tail. 512 threads, 128 KiB LDS.
__global__ __launch_bounds__(512, 2)
void k_body256_router(const bf16_t* __restrict__ xb, const bf16_t* __restrict__ W1t,
                      const float* __restrict__ bb1, bf16_t* __restrict__ hbuf,
                      const bf16_t* __restrict__ xlo,
                      const bf16_t* __restrict__ R1h, const bf16_t* __restrict__ R1l,
                      const float* __restrict__ Rb1, float* __restrict__ hr,
                      int nbody)
{
  __shared__ __align__(128) char sm[131072];
  const int g = blockIdx.x;
  if (g < nbody) {
    // XCD-aware: xcd = g&7 owns 64 consecutive wgids; mt fastest -> B-reuse
    const int wgid = ((g & 7) << 6) | (g >> 3);
    body_tile256(wgid & 31, wgid >> 5, xb, W1t, bb1, hbuf, DFF, HDIM, sm);
  } else {
    int mt, nt;
    remap_tile(g - nbody, mt, nt);
    router_tile512(mt, nt, xb, xlo, R1h, R1l, Rb1, hr,
                   (bf16_t*)sm, (bf16_t*)(sm + 8192),
                   (bf16_t*)(sm + 16384), (bf16_t*)(sm + 24576));
  }
}

// ---------------------------------------------------------------------------
// ACT: one wave per token, fp32 logit + exact halting update (in-place state).
// ---------------------------------------------------------------------------
__global__ void act_kernel(const float* __restrict__ Hr,
                           const float* __restrict__ rw2, const float* __restrict__ rb2,
                           float* __restrict__ cum_p, float* __restrict__ still_r,
                           float* __restrict__ wsum, float* __restrict__ wvec)
{
  const int t = blockIdx.x * 4 + (threadIdx.x >> 6);
  const int lane = threadIdx.x & 63;
  float s = 0.f;
#pragma unroll
  for (int j = 0; j < 8; ++j) {
    const int m = lane + j * 64;
    s += Hr[(size_t)t * RHID + m] * rw2[m];
  }
  for (int off = 32; off > 0; off >>= 1) s += __shfl_down(s, off, 64);
  if (lane == 0) {
    const float logit = s + rb2[0];
    const float p = 1.f / (1.f + expf(-logit));
    const float cum = cum_p[t];
    const float still = still_r[t];
    const float rem = fmaxf(1.f - cum, 0.f);
    const bool halt = (cum + p) >= 0.99f;
    const float w = (halt ? rem : p) * still;
    wvec[t] = w;
    wsum[t] += w;
    cum_p[t] = cum + w;
    if (halt) still_r[t] = 0.f;
  }
}

// ---------------------------------------------------------------------------
// Fused prep: Wb1/Wb2/Rw1 transposes + x->bf16 convert + ACT state init.
// ---------------------------------------------------------------------------
__device__ __forceinline__ void transpose_tile(
    const float* __restrict__ src, int srcld, int dstld,
    bf16_t* __restrict__ dst, bf16_t* __restrict__ dlo,
    int bx, int by, float* tile /* 32x33 */)
{
  const int tx = threadIdx.x & 31;
  const int ty = threadIdx.x >> 5;
#pragma unroll
  for (int l = 0; l < 4; ++l)
    tile[(ty + l * 8) * 33 + tx] = src[(size_t)(by * 32 + ty + l * 8) * srcld + bx * 32 + tx];
  __syncthreads();
#pragma unroll
  for (int l = 0; l < 4; ++l) {
    const int c = bx * 32 + ty + l * 8;
    const int r = by * 32 + tx;
    const float v = tile[tx * 33 + ty + l * 8];
    const bf16_t hi = (bf16_t)v;
    dst[(size_t)c * dstld + r] = hi;
    if (dlo) dlo[(size_t)c * dstld + r] = (bf16_t)(v - (float)hi);
  }
}

__global__ void prep_kernel(const float* __restrict__ x,
                            const float* __restrict__ Wb1,
                            const float* __restrict__ Wb2,
                            const float* __restrict__ Rw1,
                            bf16_t* __restrict__ xb,
                            bf16_t* __restrict__ W1t, bf16_t* __restrict__ W2t,
                            bf16_t* __restrict__ R1h, bf16_t* __restrict__ R1l,
                            float* __restrict__ cum0, float* __restrict__ stil0,
                            float* __restrict__ wsum0)
{
  __shared__ float tile[32 * 33];
  const int g = blockIdx.x;
  if (g < 4096) {                       // Wb1 (H x DFF) -> W1t (DFF x H)
    transpose_tile(Wb1, DFF, HDIM, W1t, nullptr, g & 127, g >> 7, tile);
  } else if (g < 8192) {                // Wb2 (DFF x H) -> W2t (H x DFF)
    const int g2 = g - 4096;
    transpose_tile(Wb2, HDIM, DFF, W2t, nullptr, g2 & 31, g2 >> 5, tile);
  } else if (g < 9728) {                // Rw1[i] (first 1024 of 1025 rows) -> hi/lo
    const int g3 = g - 8192;
    const int i  = g3 >> 9;
    const int r  = g3 & 511;
    transpose_tile(Rw1 + (size_t)i * 1025 * RHID, RHID, HDIM,
                   R1h + (size_t)i * RHID * HDIM, R1l + (size_t)i * RHID * HDIM,
                   r & 15, r >> 4, tile);
  } else if (g < 17920) {               // x fp32 -> xb bf16 (vectorized)
    const int i = (g - 9728) * 256 + threadIdx.x;
    const float4 v = ((const float4*)x)[i];
    bf16x4 hb;
    hb[0] = (bf16_t)v.x; hb[1] = (bf16_t)v.y; hb[2] = (bf16_t)v.z; hb[3] = (bf16_t)v.w;
    ((bf16x4*)xb)[i] = hb;
  } else {                              // ACT state init
    const int t = (g - 17920) * 256 + threadIdx.x;
    cum0[t] = 0.f; stil0[t] = 1.f; wsum0[t] = 1.f;
  }
}

__global__ void finalize_kernel(const float* __restrict__ wsum, float* __restrict__ out)
{
  __shared__ float red[256];
  float s = 0.f;
  for (int i = threadIdx.x; i < NTOK; i += 256) s += wsum[i];
  red[threadIdx.x] = s;
  __syncthreads();
  for (int o = 128; o > 0; o >>= 1) {
    if (threadIdx.x < o) red[threadIdx.x] += red[threadIdx.x + o];
    __syncthreads();
  }
  if (threadIdx.x == 0) {
    const float avg = red[0] / (float)NTOK;
    float d = avg - 2.5f;
    d = fmaxf(d, 0.f);
    out[0] = 0.01f * d * d;
  }
}

extern "C" void kernel_launch(void* const* d_in, const int* in_sizes, int n_in,
                              void* d_out, int out_size, void* d_ws, size_t ws_size,
                              hipStream_t stream) {
  const float* x   = (const float*)d_in[0];
  const float* Wb1 = (const float*)d_in[1];
  const float* bb1 = (const float*)d_in[2];
  const float* Wb2 = (const float*)d_in[3];
  const float* bb2 = (const float*)d_in[4];
  const float* Rw1 = (const float*)d_in[5];  // (3, 1025, 512)
  const float* Rb1 = (const float*)d_in[6];  // (3, 512)
  const float* Rw2 = (const float*)d_in[7];  // (3, 512)
  const float* Rb2 = (const float*)d_in[8];  // (3,)
  float* out = (float*)d_out;

  char* ws = (char*)d_ws;
  size_t off = 0;
  auto carve = [&](size_t bytes) -> void* {
    void* p = ws + off;
    off += (bytes + 255) & ~(size_t)255;
    return p;
  };
  bf16_t* xb   = (bf16_t*)carve((size_t)NTOK * HDIM * 2);
  bf16_t* xlo  = (bf16_t*)carve((size_t)NTOK * HDIM * 2);
  bf16_t* hbuf = (bf16_t*)carve((size_t)NTOK * DFF * 2);
  bf16_t* W1t  = (bf16_t*)carve((size_t)HDIM * DFF * 2);
  bf16_t* W2t  = (bf16_t*)carve((size_t)HDIM * DFF * 2);
  bf16_t* R1h  = (bf16_t*)carve((size_t)3 * RHID * HDIM * 2);
  bf16_t* R1l  = (bf16_t*)carve((size_t)3 * RHID * HDIM * 2);
  float*  hr   = (float*)carve((size_t)NTOK * RHID * 4);
  float*  cum  = (float*)carve((size_t)NTOK * 4);
  float*  stil = (float*)carve((size_t)NTOK * 4);
  float*  wsum = (float*)carve((size_t)NTOK * 4);
  float*  wvec = (float*)carve((size_t)NTOK * 4);

  prep_kernel<<<17952, 256, 0, stream>>>(x, Wb1, Wb2, Rw1, xb, W1t, W2t,
                                         R1h, R1l, cum, stil, wsum);

  // mandatory first body: x = body(x); x kept as hi/lo bf16 pair
  k_body256_router<<<512, 512, 0, stream>>>(xb, W1t, bb1, hbuf, xlo,
                                            nullptr, nullptr, nullptr, nullptr, 512);
  k_gemm<1, false><<<512, 256, 0, stream>>>(hbuf, W2t, bb2, HDIM, DFF,
                                            nullptr, xb, xlo, nullptr);

  for (int i = 0; i < 3; ++i) {
    k_body256_router<<<512 + 256, 512, 0, stream>>>(
        xb, W1t, bb1, hbuf, xlo,
        R1h + (size_t)i * RHID * HDIM, R1l + (size_t)i * RHID * HDIM,
        Rb1 + (size_t)i * RHID, hr, 512);
    act_kernel<<<2048, 256, 0, stream>>>(hr, Rw2 + (size_t)i * RHID, Rb2 + i,
                                         cum, stil, wsum, wvec);
    if (i < 2)
      k_gemm<2, false><<<512, 256, 0, stream>>>(hbuf, W2t, bb2, HDIM, DFF,
                                                nullptr, xb, xlo, wvec);
    else
      k_gemm<2, true><<<512, 256, 0, stream>>>(hbuf, W2t, bb2, HDIM, DFF,
                                               out, xb, xlo, wvec);
  }

  finalize_kernel<<<1, 256, 0, stream>>>(wsum, out + (size_t)NTOK * HDIM);
  (void)in_sizes; (void)n_in; (void)out_size; (void)ws_size;
}

// Round 2
// 870.080 us; speedup vs baseline: 1.0149x; 1.0149x over previous
//
#include <hip/hip_runtime.h>
#include <hip/hip_bf16.h>
#include <math.h>

typedef __bf16 bf16_t;
typedef __attribute__((ext_vector_type(8))) __bf16 bf16x8;
typedef __attribute__((ext_vector_type(4))) __bf16 bf16x4;
typedef __attribute__((ext_vector_type(4))) float f32x4;

#define NTOK 8192   // B*T
#define HDIM 1024
#define DFF  4096
#define RHID 512

__device__ __forceinline__ float gelu_exact(float v) {
  return 0.5f * v * (1.0f + erff(v * 0.70710678118654752f));
}

// tanh-form gelu via sigmoid; max abs err ~3e-4 (noise vs bf16 quantization).
__device__ __forceinline__ float gelu_fast(float v) {
  const float g = 1.5957691216057308f * (v + 0.044715f * v * v * v);
  return v / (1.0f + __expf(-g));
}

__device__ __forceinline__ void async_cp16(void* lds, const void* g) {
  __builtin_amdgcn_global_load_lds(
      (__attribute__((address_space(1))) void*)g,
      (__attribute__((address_space(3))) void*)lds, 16, 0, 0);
}

// XCD-aware remap for 128x128 tile grids (router + k_gemm).
__device__ __forceinline__ void remap_tile(int g, int& mt, int& nt) {
  mt = ((g & 7) << 3) | ((g >> 3) & 7);
  nt = g >> 6;
}

// ---------------------------------------------------------------------------
// GEMM1 256x256 tile, BK=64, 8 waves (2x4), double-buffered 128 KiB LDS.
// Revised 4-phase schedule (r1 post-mortem):
//  - ALL 8 global_load_lds for tile t+1 issued at top of P1(t) (batch),
//    order A0,B0,B1,A1. Waits: vmcnt(10)@end-P1 (B1(t), ~4 phases after
//    issue), vmcnt(8)@end-P2 (A1(t), ~5 phases), vmcnt(4)@end-P4
//    (A0/B0(t+1), ~3 phases). Never drains to 0 in-loop; <=12 in flight.
//  - 3 barriers/tile (publication points only), compiler fence after each.
//  - P3+P4 merged into one 32-MFMA cluster (P4 reads registers only).
// LDS per buffer: A/B = 2 halves x 128 rows x 8 slots x 16B; LDS row r slot s
// holds global k-slot (s ^ (r&7)) — swizzle applied on the GLOBAL source so
// global_load_lds writes linearly (m173 pattern).
// ---------------------------------------------------------------------------
__device__ __forceinline__ void body_tile256(
    int mt, int nt,
    const bf16_t* __restrict__ A, const bf16_t* __restrict__ Bt,
    const float* __restrict__ bias, bf16_t* __restrict__ Hout,
    int N, int K, char* sm)
{
  const int tid  = threadIdx.x;
  const int lane = tid & 63;
  const int wv   = tid >> 6;      // 0..7
  const int wm   = wv >> 2;       // 0..1
  const int wn   = wv & 3;        // 0..3
  const int lr   = lane & 15;
  const int quad = lane >> 4;
  const int m0 = mt * 256;
  const int n0 = nt * 256;

  char* const Ab0 = sm;
  char* const Bb0 = sm + 32768;
  char* const Ab1 = sm + 65536;
  char* const Bb1 = sm + 98304;

  // read-side swizzled slot offsets (rl&7 == lr&7 for all our frag rows)
  const int sw0 = ((quad ^ (lr & 7)) << 4);
  const int sw1 = (((quad + 4) ^ (lr & 7)) << 4);
  const int aRowB = (wm * 64 + lr) << 7;   // + mh*16384 + i*2048
  const int bRowB = (wn * 32 + lr) << 7;   // + nh*16384 + j*2048

  f32x4 acc[8][4];
#pragma unroll
  for (int i = 0; i < 8; ++i)
#pragma unroll
    for (int j = 0; j < 4; ++j)
      acc[i][j] = (f32x4){0.f, 0.f, 0.f, 0.f};

  // staging sources (pre-swizzled k-slot within each row)
  const int srow = tid >> 3;                          // 0..63
  const int seo  = (((tid & 7) ^ (srow & 7)) << 3);   // elems
  const bf16_t* const aS00 = A + (size_t)(m0 +       srow) * K + seo;
  const bf16_t* const aS01 = A + (size_t)(m0 + 128 + srow) * K + seo;
  const bf16_t* const aS10 = A + (size_t)(m0 +  64 + srow) * K + seo;
  const bf16_t* const aS11 = A + (size_t)(m0 + 192 + srow) * K + seo;
  const int bc0 = ((srow >> 5) << 6) + (srow & 31);   // {0..31, 64..95}
  const bf16_t* const bS00 = Bt + (size_t)(n0 +       bc0) * K + seo;
  const bf16_t* const bS01 = Bt + (size_t)(n0 + 128 + bc0) * K + seo;
  const bf16_t* const bS10 = Bt + (size_t)(n0 +  32 + bc0) * K + seo;
  const bf16_t* const bS11 = Bt + (size_t)(n0 + 160 + bc0) * K + seo;
  const int dst = tid << 4;

  // prologue: tile-0 batch into buf0, order A0,B0,B1,A1 (matches loop)
  async_cp16(Ab0 + dst,                aS00);
  async_cp16(Ab0 + dst + 8192,         aS01);
  async_cp16(Bb0 + dst,                bS00);
  async_cp16(Bb0 + dst + 8192,         bS01);
  async_cp16(Bb0 + 16384 + dst,        bS10);
  async_cp16(Bb0 + 16384 + dst + 8192, bS11);
  async_cp16(Ab0 + 16384 + dst,        aS10);
  async_cp16(Ab0 + 16384 + dst + 8192, aS11);
  asm volatile("s_waitcnt vmcnt(4)" ::: "memory");   // A0,B0 of tile 0 landed
  __builtin_amdgcn_s_barrier();
  asm volatile("" ::: "memory");

  bf16x8 a0[4], a1[4], b00[2], b01[2], b10[2], b11[2];

  const int NT = K >> 6;
  for (int t = 0; t < NT; ++t) {
    char* const Ac = (t & 1) ? Ab1 : Ab0;
    char* const Bc = (t & 1) ? Bb1 : Bb0;
    char* const An = (t & 1) ? Ab0 : Ab1;
    char* const Bn = (t & 1) ? Bb0 : Bb1;
    // last tile: re-stage current addresses (valid, never read) to keep counts
    const size_t kbn = (size_t)((t + 1 < NT) ? t + 1 : t) << 6;

    // ---- P1: batch-issue tile t+1 (8 loads); ds_read A-half0 + B-half0;
    //          MFMA Q(mh0,nh0) ----
    async_cp16(An + dst,                aS00 + kbn);
    async_cp16(An + dst + 8192,         aS01 + kbn);
    async_cp16(Bn + dst,                bS00 + kbn);
    async_cp16(Bn + dst + 8192,         bS01 + kbn);
    async_cp16(Bn + 16384 + dst,        bS10 + kbn);
    async_cp16(Bn + 16384 + dst + 8192, bS11 + kbn);
    async_cp16(An + 16384 + dst,        aS10 + kbn);
    async_cp16(An + 16384 + dst + 8192, aS11 + kbn);
#pragma unroll
    for (int i = 0; i < 4; ++i) {
      const char* p = Ac + aRowB + i * 2048;
      a0[i] = *(const bf16x8*)(p + sw0);
      a1[i] = *(const bf16x8*)(p + sw1);
    }
#pragma unroll
    for (int j = 0; j < 2; ++j) {
      const char* p = Bc + bRowB + j * 2048;
      b00[j] = *(const bf16x8*)(p + sw0);
      b01[j] = *(const bf16x8*)(p + sw1);
    }
    __builtin_amdgcn_s_setprio(1);
#pragma unroll
    for (int i = 0; i < 4; ++i)
#pragma unroll
      for (int j = 0; j < 2; ++j) {
        acc[i][j] = __builtin_amdgcn_mfma_f32_16x16x32_bf16(a0[i], b00[j], acc[i][j], 0, 0, 0);
        acc[i][j] = __builtin_amdgcn_mfma_f32_16x16x32_bf16(a1[i], b01[j], acc[i][j], 0, 0, 0);
      }
    __builtin_amdgcn_s_setprio(0);
    // retire B1(t) (issued P1(t-1), 4 phases ago); keep A1(t)+batch(t+1)
    asm volatile("s_waitcnt vmcnt(10)" ::: "memory");
    __builtin_amdgcn_s_barrier();
    asm volatile("" ::: "memory");

    // ---- P2: ds_read B-half1; MFMA Q(mh0,nh1) ----
#pragma unroll
    for (int j = 0; j < 2; ++j) {
      const char* p = Bc + 16384 + bRowB + j * 2048;
      b10[j] = *(const bf16x8*)(p + sw0);
      b11[j] = *(const bf16x8*)(p + sw1);
    }
    __builtin_amdgcn_s_setprio(1);
#pragma unroll
    for (int i = 0; i < 4; ++i)
#pragma unroll
      for (int j = 0; j < 2; ++j) {
        acc[i][2+j] = __builtin_amdgcn_mfma_f32_16x16x32_bf16(a0[i], b10[j], acc[i][2+j], 0, 0, 0);
        acc[i][2+j] = __builtin_amdgcn_mfma_f32_16x16x32_bf16(a1[i], b11[j], acc[i][2+j], 0, 0, 0);
      }
    __builtin_amdgcn_s_setprio(0);
    // retire A1(t) (issued P1(t-1), 5 phases ago); keep batch(t+1)
    asm volatile("s_waitcnt vmcnt(8)" ::: "memory");
    __builtin_amdgcn_s_barrier();
    asm volatile("" ::: "memory");

    // ---- P3+P4: ds_read A-half1; MFMA Q(mh1,nh1) then Q(mh1,nh0) ----
#pragma unroll
    for (int i = 0; i < 4; ++i) {
      const char* p = Ac + 16384 + aRowB + i * 2048;
      a0[i] = *(const bf16x8*)(p + sw0);
      a1[i] = *(const bf16x8*)(p + sw1);
    }
    __builtin_amdgcn_s_setprio(1);
#pragma unroll
    for (int i = 0; i < 4; ++i)
#pragma unroll
      for (int j = 0; j < 2; ++j) {
        acc[4+i][2+j] = __builtin_amdgcn_mfma_f32_16x16x32_bf16(a0[i], b10[j], acc[4+i][2+j], 0, 0, 0);
        acc[4+i][2+j] = __builtin_amdgcn_mfma_f32_16x16x32_bf16(a1[i], b11[j], acc[4+i][2+j], 0, 0, 0);
      }
#pragma unroll
    for (int i = 0; i < 4; ++i)
#pragma unroll
      for (int j = 0; j < 2; ++j) {
        acc[4+i][j] = __builtin_amdgcn_mfma_f32_16x16x32_bf16(a0[i], b00[j], acc[4+i][j], 0, 0, 0);
        acc[4+i][j] = __builtin_amdgcn_mfma_f32_16x16x32_bf16(a1[i], b01[j], acc[4+i][j], 0, 0, 0);
      }
    __builtin_amdgcn_s_setprio(0);
    // retire A0,B0(t+1) (issued P1(t), ~3 phases ago); keep B1,A1(t+1)
    asm volatile("s_waitcnt vmcnt(4)" ::: "memory");
    __builtin_amdgcn_s_barrier();
    asm volatile("" ::: "memory");
  }
  // drain pending LDS DMA before wave exit (LDS may be reassigned)
  asm volatile("s_waitcnt vmcnt(0)" ::: "memory");

  // epilogue: gelu -> bf16 (MODE 0 semantics, numerics identical to old path)
#pragma unroll
  for (int mh = 0; mh < 2; ++mh)
#pragma unroll
    for (int i = 0; i < 4; ++i)
#pragma unroll
      for (int r = 0; r < 4; ++r) {
        const int gm = m0 + wm * 128 + mh * 64 + i * 16 + quad * 4 + r;
        bf16_t* const orow = Hout + (size_t)gm * N + n0 + wn * 64 + lr;
#pragma unroll
        for (int nh = 0; nh < 2; ++nh)
#pragma unroll
          for (int j = 0; j < 2; ++j) {
            const int cn = nh * 32 + j * 16;
            const float v = acc[mh * 4 + i][nh * 2 + j][r] + bias[n0 + wn * 64 + cn + lr];
            orow[cn] = (bf16_t)gelu_fast(v);
          }
      }
}

// ---------------------------------------------------------------------------
// GEMM tile for k_gemm (MODE 1/2), unchanged proven r4 structure.
// ---------------------------------------------------------------------------
template<int MODE, bool WRITE_OUT, int WM, int WN>
__device__ __forceinline__ void body_tile(
    int mt, int nt,
    const bf16_t* __restrict__ A, const bf16_t* __restrict__ Bt,
    const float* __restrict__ bias, int N, int K,
    bf16_t* __restrict__ Hout, float* __restrict__ Xout,
    bf16_t* __restrict__ Xb, bf16_t* __restrict__ Xlo,
    const float* __restrict__ Wmix,
    bf16_t* As, bf16_t* Bs)
{
  constexpr int BM  = WM * 32;
  constexpr int BN  = WN * 32;
  constexpr int ACH = BM / 32;
  constexpr int BCH = BN / 32;
  const int tid  = threadIdx.x;
  const int lane = tid & 63;
  const int wv   = tid >> 6;
  const int wm   = wv >> 1;
  const int wn   = wv & 1;
  const int lr   = lane & 15;
  const int quad = lane >> 4;
  const int m0 = mt * BM;
  const int n0 = nt * BN;

  f32x4 acc[WM][WN];
#pragma unroll
  for (int i = 0; i < WM; ++i)
#pragma unroll
    for (int j = 0; j < WN; ++j)
      acc[i][j] = (f32x4){0.f, 0.f, 0.f, 0.f};

  const int c   = tid;
  const int row = c >> 3;
  const int ks  = (((c & 7) - (row & 7)) & 7) * 8;
  const bf16_t* Agb = A  + (size_t)(m0 + row) * K + ks;
  const bf16_t* Bgb = Bt + (size_t)(n0 + row) * K + ks;
  char* lAb = (char*)As + c * 16;
  char* lBb = (char*)Bs + c * 16;

  for (int kb = 0; kb < K; kb += 64) {
    __syncthreads();
#pragma unroll
    for (int t = 0; t < ACH; ++t)
      async_cp16(lAb + 4096 * t, Agb + (size_t)32 * t * K + kb);
#pragma unroll
    for (int t = 0; t < BCH; ++t)
      async_cp16(lBb + 4096 * t, Bgb + (size_t)32 * t * K + kb);
    __syncthreads();
#pragma unroll
    for (int kk = 0; kk < 2; ++kk) {
      const int kg = kk * 4 + quad;
      bf16x8 af[WM], bfr[WN];
#pragma unroll
      for (int i = 0; i < WM; ++i) {
        const int ra = wm * (WM * 16) + i * 16 + lr;
        af[i] = *(const bf16x8*)&As[ra * 64 + ((kg + ra) & 7) * 8];
      }
#pragma unroll
      for (int j = 0; j < WN; ++j) {
        const int rb = wn * (WN * 16) + j * 16 + lr;
        bfr[j] = *(const bf16x8*)&Bs[rb * 64 + ((kg + rb) & 7) * 8];
      }
#pragma unroll
      for (int i = 0; i < WM; ++i)
#pragma unroll
        for (int j = 0; j < WN; ++j)
          acc[i][j] = __builtin_amdgcn_mfma_f32_16x16x32_bf16(af[i], bfr[j], acc[i][j], 0, 0, 0);
    }
  }

#pragma unroll
  for (int i = 0; i < WM; ++i) {
#pragma unroll
    for (int r = 0; r < 4; ++r) {
      const int gm = m0 + wm * (WM * 16) + i * 16 + quad * 4 + r;
      float wmix = 0.f, onemw = 0.f;
      if (MODE == 2) { wmix = Wmix[gm]; onemw = 1.f - wmix; }
#pragma unroll
      for (int j = 0; j < WN; ++j) {
        const int gn = n0 + wn * (WN * 16) + j * 16 + lr;
        float v = acc[i][j][r] + bias[gn];
        if (MODE == 0) {
          Hout[(size_t)gm * N + gn] = (bf16_t)gelu_fast(v);
        } else {
          const size_t idx = (size_t)gm * N + gn;
          if (MODE == 2) {
            const float xold = (float)Xb[idx] + (float)Xlo[idx];
            v = wmix * v + onemw * xold;
          }
          const bf16_t hi = (bf16_t)v;
          Xb[idx]  = hi;
          Xlo[idx] = (bf16_t)(v - (float)hi);
          if (WRITE_OUT) Xout[idx] = v;
        }
      }
    }
  }
}

// ---------------------------------------------------------------------------
// Router tile (hi/lo split ~fp32) for 512-thread blocks: 8 waves 2x4,
// BK=32 single-buffered, 32KB LDS. acc = Ah*Bh + Al*Bh + Ah*Bl.
// ---------------------------------------------------------------------------
__device__ __forceinline__ void router_tile512(
    int mt, int nt,
    const bf16_t* __restrict__ Ah, const bf16_t* __restrict__ Al,
    const bf16_t* __restrict__ Bh, const bf16_t* __restrict__ Bl,
    const float* __restrict__ bias, float* __restrict__ Hr,
    bf16_t* Ahs, bf16_t* Als, bf16_t* Bhs, bf16_t* Bls)
{
  const int K = HDIM, N = RHID;
  const int tid  = threadIdx.x;
  const int lane = tid & 63;
  const int wv   = tid >> 6;
  const int wm   = wv >> 2;   // 0..1
  const int wn   = wv & 3;    // 0..3
  const int lr   = lane & 15;
  const int quad = lane >> 4;
  const int m0 = mt * 128;
  const int n0 = nt * 128;

  f32x4 acc[4][2];
#pragma unroll
  for (int i = 0; i < 4; ++i)
#pragma unroll
    for (int j = 0; j < 2; ++j)
      acc[i][j] = (f32x4){0.f, 0.f, 0.f, 0.f};

  const int r   = tid >> 2;                 // 0..127
  const int ks  = ((tid ^ r) & 3) * 8;
  const size_t aoff = (size_t)(m0 + r) * K + ks;
  const size_t boff = (size_t)(n0 + r) * K + ks;
  const int dst = tid << 4;
  const int sw  = ((quad ^ lr) & 3) * 8;

  for (int k0 = 0; k0 < K; k0 += 32) {
    __syncthreads();
    async_cp16((char*)Ahs + dst, Ah + aoff + k0);
    async_cp16((char*)Als + dst, Al + aoff + k0);
    async_cp16((char*)Bhs + dst, Bh + boff + k0);
    async_cp16((char*)Bls + dst, Bl + boff + k0);
    __syncthreads();
    bf16x8 ah[4], al[4], bh[2], bl[2];
#pragma unroll
    for (int i = 0; i < 4; ++i) {
      const int ao = (wm * 64 + i * 16 + lr) * 32 + sw;
      ah[i] = *(const bf16x8*)&Ahs[ao];
      al[i] = *(const bf16x8*)&Als[ao];
    }
#pragma unroll
    for (int j = 0; j < 2; ++j) {
      const int bo = (wn * 32 + j * 16 + lr) * 32 + sw;
      bh[j] = *(const bf16x8*)&Bhs[bo];
      bl[j] = *(const bf16x8*)&Bls[bo];
    }
#pragma unroll
    for (int i = 0; i < 4; ++i)
#pragma unroll
      for (int j = 0; j < 2; ++j) {
        acc[i][j] = __builtin_amdgcn_mfma_f32_16x16x32_bf16(ah[i], bh[j], acc[i][j], 0, 0, 0);
        acc[i][j] = __builtin_amdgcn_mfma_f32_16x16x32_bf16(al[i], bh[j], acc[i][j], 0, 0, 0);
        acc[i][j] = __builtin_amdgcn_mfma_f32_16x16x32_bf16(ah[i], bl[j], acc[i][j], 0, 0, 0);
      }
  }

#pragma unroll
  for (int i = 0; i < 4; ++i)
#pragma unroll
    for (int rr = 0; rr < 4; ++rr) {
      const int gm = m0 + wm * 64 + i * 16 + quad * 4 + rr;
#pragma unroll
      for (int j = 0; j < 2; ++j) {
        const int gn = n0 + wn * 32 + j * 16 + lr;
        Hr[(size_t)gm * N + gn] = gelu_exact(acc[i][j][rr] + bias[gn]);
      }
    }
}

// MODE1/MODE2 standalone GEMM, 128x128 tiles (512 blocks), 32KB LDS
template<int MODE, bool WRITE_OUT>
__global__ __launch_bounds__(256, 4)
void k_gemm(const bf16_t* __restrict__ A, const bf16_t* __restrict__ Bt,
            const float* __restrict__ bias, int N, int K,
            float* __restrict__ Xout, bf16_t* __restrict__ Xb,
            bf16_t* __restrict__ Xlo, const float* __restrict__ Wmix)
{
  __shared__ __align__(16) bf16_t sm[16384];
  int mt, nt;
  remap_tile(blockIdx.x, mt, nt);
  body_tile<MODE, WRITE_OUT, 4, 4>(mt, nt, A, Bt, bias, N, K,
                                   nullptr, Xout, Xb, Xlo, Wmix, sm, sm + 8192);
}

// GEMM1 (256^2 4-phase batch-prefetch) + fused router tail. 512 thr, 128 KiB.
__global__ __launch_bounds__(512, 2)
void k_body256_router(const bf16_t* __restrict__ xb, const bf16_t* __restrict__ W1t,
                      const float* __restrict__ bb1, bf16_t* __restrict__ hbuf,
                      const bf16_t* __restrict__ xlo,
                      const bf16_t* __restrict__ R1h, const bf16_t* __restrict__ R1l,
                      const float* __restrict__ Rb1, float* __restrict__ hr,
                      int nbody)
{
  __shared__ __align__(128) char sm[131072];
  const int g = blockIdx.x;
  if (g < nbody) {
    // XCD-aware: each XCD (g&7) owns a 4-mt strip (2MB A, L2-resident);
    // mt_local fastest so co-resident blocks share B columns; nt slowest.
    const int mt = ((g & 7) << 2) | ((g >> 3) & 3);
    const int nt = g >> 5;
    body_tile256(mt, nt, xb, W1t, bb1, hbuf, DFF, HDIM, sm);
  } else {
    int mt, nt;
    remap_tile(g - nbody, mt, nt);
    router_tile512(mt, nt, xb, xlo, R1h, R1l, Rb1, hr,
                   (bf16_t*)sm, (bf16_t*)(sm + 8192),
                   (bf16_t*)(sm + 16384), (bf16_t*)(sm + 24576));
  }
}

// ---------------------------------------------------------------------------
// ACT: one wave per token, fp32 logit + exact halting update (in-place state).
// ---------------------------------------------------------------------------
__global__ void act_kernel(const float* __restrict__ Hr,
                           const float* __restrict__ rw2, const float* __restrict__ rb2,
                           float* __restrict__ cum_p, float* __restrict__ still_r,
                           float* __restrict__ wsum, float* __restrict__ wvec)
{
  const int t = blockIdx.x * 4 + (threadIdx.x >> 6);
  const int lane = threadIdx.x & 63;
  float s = 0.f;
#pragma unroll
  for (int j = 0; j < 8; ++j) {
    const int m = lane + j * 64;
    s += Hr[(size_t)t * RHID + m] * rw2[m];
  }
  for (int off = 32; off > 0; off >>= 1) s += __shfl_down(s, off, 64);
  if (lane == 0) {
    const float logit = s + rb2[0];
    const float p = 1.f / (1.f + expf(-logit));
    const float cum = cum_p[t];
    const float still = still_r[t];
    const float rem = fmaxf(1.f - cum, 0.f);
    const bool halt = (cum + p) >= 0.99f;
    const float w = (halt ? rem : p) * still;
    wvec[t] = w;
    wsum[t] += w;
    cum_p[t] = cum + w;
    if (halt) still_r[t] = 0.f;
  }
}

// ---------------------------------------------------------------------------
// Fused prep: Wb1/Wb2/Rw1 transposes + x->bf16 convert + ACT state init.
// ---------------------------------------------------------------------------
__device__ __forceinline__ void transpose_tile(
    const float* __restrict__ src, int srcld, int dstld,
    bf16_t* __restrict__ dst, bf16_t* __restrict__ dlo,
    int bx, int by, float* tile /* 32x33 */)
{
  const int tx = threadIdx.x & 31;
  const int ty = threadIdx.x >> 5;
#pragma unroll
  for (int l = 0; l < 4; ++l)
    tile[(ty + l * 8) * 33 + tx] = src[(size_t)(by * 32 + ty + l * 8) * srcld + bx * 32 + tx];
  __syncthreads();
#pragma unroll
  for (int l = 0; l < 4; ++l) {
    const int c = bx * 32 + ty + l * 8;
    const int r = by * 32 + tx;
    const float v = tile[tx * 33 + ty + l * 8];
    const bf16_t hi = (bf16_t)v;
    dst[(size_t)c * dstld + r] = hi;
    if (dlo) dlo[(size_t)c * dstld + r] = (bf16_t)(v - (float)hi);
  }
}

__global__ void prep_kernel(const float* __restrict__ x,
                            const float* __restrict__ Wb1,
                            const float* __restrict__ Wb2,
                            const float* __restrict__ Rw1,
                            bf16_t* __restrict__ xb,
                            bf16_t* __restrict__ W1t, bf16_t* __restrict__ W2t,
                            bf16_t* __restrict__ R1h, bf16_t* __restrict__ R1l,
                            float* __restrict__ cum0, float* __restrict__ stil0,
                            float* __restrict__ wsum0)
{
  __shared__ float tile[32 * 33];
  const int g = blockIdx.x;
  if (g < 4096) {                       // Wb1 (H x DFF) -> W1t (DFF x H)
    transpose_tile(Wb1, DFF, HDIM, W1t, nullptr, g & 127, g >> 7, tile);
  } else if (g < 8192) {                // Wb2 (DFF x H) -> W2t (H x DFF)
    const int g2 = g - 4096;
    transpose_tile(Wb2, HDIM, DFF, W2t, nullptr, g2 & 31, g2 >> 5, tile);
  } else if (g < 9728) {                // Rw1[i] (first 1024 of 1025 rows) -> hi/lo
    const int g3 = g - 8192;
    const int i  = g3 >> 9;
    const int r  = g3 & 511;
    transpose_tile(Rw1 + (size_t)i * 1025 * RHID, RHID, HDIM,
                   R1h + (size_t)i * RHID * HDIM, R1l + (size_t)i * RHID * HDIM,
                   r & 15, r >> 4, tile);
  } else if (g < 17920) {               // x fp32 -> xb bf16 (vectorized)
    const int i = (g - 9728) * 256 + threadIdx.x;
    const float4 v = ((const float4*)x)[i];
    bf16x4 hb;
    hb[0] = (bf16_t)v.x; hb[1] = (bf16_t)v.y; hb[2] = (bf16_t)v.z; hb[3] = (bf16_t)v.w;
    ((bf16x4*)xb)[i] = hb;
  } else {                              // ACT state init
    const int t = (g - 17920) * 256 + threadIdx.x;
    cum0[t] = 0.f; stil0[t] = 1.f; wsum0[t] = 1.f;
  }
}

__global__ void finalize_kernel(const float* __restrict__ wsum, float* __restrict__ out)
{
  __shared__ float red[256];
  float s = 0.f;
  for (int i = threadIdx.x; i < NTOK; i += 256) s += wsum[i];
  red[threadIdx.x] = s;
  __syncthreads();
  for (int o = 128; o > 0; o >>= 1) {
    if (threadIdx.x < o) red[threadIdx.x] += red[threadIdx.x + o];
    __syncthreads();
  }
  if (threadIdx.x == 0) {
    const float avg = red[0] / (float)NTOK;
    float d = avg - 2.5f;
    d = fmaxf(d, 0.f);
    out[0] = 0.01f * d * d;
  }
}

extern "C" void kernel_launch(void* const* d_in, const int* in_sizes, int n_in,
                              void* d_out, int out_size, void* d_ws, size_t ws_size,
                              hipStream_t stream) {
  const float* x   = (const float*)d_in[0];
  const float* Wb1 = (const float*)d_in[1];
  const float* bb1 = (const float*)d_in[2];
  const float* Wb2 = (const float*)d_in[3];
  const float* bb2 = (const float*)d_in[4];
  const float* Rw1 = (const float*)d_in[5];  // (3, 1025, 512)
  const float* Rb1 = (const float*)d_in[6];  // (3, 512)
  const float* Rw2 = (const float*)d_in[7];  // (3, 512)
  const float* Rb2 = (const float*)d_in[8];  // (3,)
  float* out = (float*)d_out;

  char* ws = (char*)d_ws;
  size_t off = 0;
  auto carve = [&](size_t bytes) -> void* {
    void* p = ws + off;
    off += (bytes + 255) & ~(size_t)255;
    return p;
  };
  bf16_t* xb   = (bf16_t*)carve((size_t)NTOK * HDIM * 2);
  bf16_t* xlo  = (bf16_t*)carve((size_t)NTOK * HDIM * 2);
  bf16_t* hbuf = (bf16_t*)carve((size_t)NTOK * DFF * 2);
  bf16_t* W1t  = (bf16_t*)carve((size_t)HDIM * DFF * 2);
  bf16_t* W2t  = (bf16_t*)carve((size_t)HDIM * DFF * 2);
  bf16_t* R1h  = (bf16_t*)carve((size_t)3 * RHID * HDIM * 2);
  bf16_t* R1l  = (bf16_t*)carve((size_t)3 * RHID * HDIM * 2);
  float*  hr   = (float*)carve((size_t)NTOK * RHID * 4);
  float*  cum  = (float*)carve((size_t)NTOK * 4);
  float*  stil = (float*)carve((size_t)NTOK * 4);
  float*  wsum = (float*)carve((size_t)NTOK * 4);
  float*  wvec = (float*)carve((size_t)NTOK * 4);

  prep_kernel<<<17952, 256, 0, stream>>>(x, Wb1, Wb2, Rw1, xb, W1t, W2t,
                                         R1h, R1l, cum, stil, wsum);

  // mandatory first body: x = body(x); x kept as hi/lo bf16 pair
  k_body256_router<<<512, 512, 0, stream>>>(xb, W1t, bb1, hbuf, xlo,
                                            nullptr, nullptr, nullptr, nullptr, 512);
  k_gemm<1, false><<<512, 256, 0, stream>>>(hbuf, W2t, bb2, HDIM, DFF,
                                            nullptr, xb, xlo, nullptr);

  for (int i = 0; i < 3; ++i) {
    k_body256_router<<<512 + 256, 512, 0, stream>>>(
        xb, W1t, bb1, hbuf, xlo,
        R1h + (size_t)i * RHID * HDIM, R1l + (size_t)i * RHID * HDIM,
        Rb1 + (size_t)i * RHID, hr, 512);
    act_kernel<<<2048, 256, 0, stream>>>(hr, Rw2 + (size_t)i * RHID, Rb2 + i,
                                         cum, stil, wsum, wvec);
    if (i < 2)
      k_gemm<2, false><<<512, 256, 0, stream>>>(hbuf, W2t, bb2, HDIM, DFF,
                                                nullptr, xb, xlo, wvec);
    else
      k_gemm<2, true><<<512, 256, 0, stream>>>(hbuf, W2t, bb2, HDIM, DFF,
                                               out, xb, xlo, wvec);
  }

  finalize_kernel<<<1, 256, 0, stream>>>(wsum, out + (size_t)NTOK * HDIM);
  (void)in_sizes; (void)n_in; (void)out_size; (void)ws_size;
}